// Round 7
// baseline (209.093 us; speedup 1.0000x reference)
//
#include <hip/hip_runtime.h>
#include <hip/hip_bf16.h>
#include <stdint.h>
#include <math.h>

typedef __attribute__((ext_vector_type(8))) __bf16 bf16x8;
typedef __attribute__((ext_vector_type(4))) float f32x4;

#define B_   32
#define TV_  1024
#define TS_  64
#define DIN_ 1024
#define D_   512

static __device__ __forceinline__ unsigned short f2bf(float f) {
    union { float f; uint32_t u; } x; x.f = f;
    uint32_t r = x.u + 0x7fffu + ((x.u >> 16) & 1u);
    return (unsigned short)(r >> 16);
}
static __device__ __forceinline__ uint32_t cvtpk(float lo, float hi) {
    uint32_t r;
    asm("v_cvt_pk_bf16_f32 %0, %1, %2" : "=v"(r) : "v"(lo), "v"(hi));
    return r;
}
static __device__ __forceinline__ void swap32(uint32_t& a, uint32_t& b) {
    asm volatile("v_permlane32_swap_b32 %0, %1" : "+v"(a), "+v"(b));
}
static __device__ __forceinline__ void swap16(uint32_t& a, uint32_t& b) {
    asm volatile("v_permlane16_swap_b32 %0, %1" : "+v"(a), "+v"(b));
}

// ---------------- K1: transpose + convert weights: Wt[w][n][k] = W[k][n] (bf16)
__global__ __launch_bounds__(256) void transpose_w(const float* __restrict__ Wv,
                                                   const float* __restrict__ Wsn,
                                                   unsigned short* __restrict__ Wt) {
    const int w = blockIdx.z;
    const float* src = w ? Wsn : Wv;
    __shared__ float t[32][33];
    const int k0 = blockIdx.x * 32, n0 = blockIdx.y * 32;
    const int tx = threadIdx.x & 31, ty = threadIdx.x >> 5;
    #pragma unroll
    for (int r = 0; r < 32; r += 8)
        t[r + ty][tx] = src[(size_t)(k0 + r + ty) * D_ + n0 + tx];
    __syncthreads();
    #pragma unroll
    for (int r = 0; r < 32; r += 8)
        Wt[(size_t)w * 524288 + (size_t)(n0 + r + ty) * DIN_ + k0 + tx] = f2bf(t[tx][r + ty]);
}

// ---------------- K2: fused encoder GEMM (video blocks 0..1023, sentence 1024..1087)
// LDS double-buffered, ONE barrier per K-step, issue-early global loads,
// XOR-swizzled A and B tiles (conflict-free ds_read_b128).
__global__ __launch_bounds__(256) void encoder_gemm(const float* __restrict__ videos,
                                                    const float* __restrict__ sentences,
                                                    const unsigned short* __restrict__ Wt,
                                                    const float* __restrict__ bv,
                                                    const float* __restrict__ bs,
                                                    unsigned short* __restrict__ Vrep,
                                                    unsigned short* __restrict__ Srep) {
    __shared__ char Asb[2][16384];
    __shared__ char Bsb[2][16384];
    const int bid = blockIdx.x;
    const float* X; const unsigned short* W; const float* bias; unsigned short* out;
    int m0, n0;
    if (bid < 1024) {
        int xcd = bid & 7, sl = bid >> 3;
        m0 = (xcd * 32 + (sl >> 2)) * 128;
        n0 = (sl & 3) * 128;
        X = videos; W = Wt; bias = bv; out = Vrep;
    } else {
        int sb = bid - 1024;
        m0 = (sb >> 2) * 128;
        n0 = (sb & 3) * 128;
        X = sentences; W = Wt + 524288; bias = bs; out = Srep;
    }
    const int tid = threadIdx.x;
    const int lane = tid & 63, wid = tid >> 6;
    const int g = lane >> 4, c = lane & 15;
    const int wm = wid >> 1, wn = wid & 1;

    // staging addresses (per-thread constants)
    const int am = tid >> 4, ak4 = tid & 15;          // A: rows am, am+16,.. (it*16)
    const int bn = tid >> 3, bkq = tid & 7;           // B: rows bn, bn+32,.. (it*32)
    const float* Ag = X + (size_t)(m0 + am) * DIN_ + ak4 * 4;
    const unsigned short* Bg = W + (size_t)(n0 + bn) * DIN_ + bkq * 8;
    char* Aw0 = &Asb[0][am * 128 + ((ak4 * 8) ^ ((am & 7) << 4))];
    char* Bw0 = &Bsb[0][bn * 128 + ((bkq * 16) ^ ((bn & 7) << 4))];

    f32x4 acc[4][4];
    {
        f32x4 z = {0.f, 0.f, 0.f, 0.f};
        #pragma unroll
        for (int a = 0; a < 4; ++a)
            #pragma unroll
            for (int b = 0; b < 4; ++b) acc[a][b] = z;
    }

    float4 av[8]; uint4 bvv[4];
    #define LOADTILE(kk) {                                                     \
        const int k0_ = (kk) * 64;                                             \
        _Pragma("unroll")                                                      \
        for (int it = 0; it < 8; ++it)                                         \
            av[it] = *(const float4*)(Ag + (size_t)(it * 16) * DIN_ + k0_);    \
        _Pragma("unroll")                                                      \
        for (int it = 0; it < 4; ++it)                                         \
            bvv[it] = *(const uint4*)(Bg + (size_t)(it * 32) * DIN_ + k0_);    \
    }
    #define WRITETILE(buf) {                                                   \
        _Pragma("unroll")                                                      \
        for (int it = 0; it < 8; ++it) {                                       \
            uint2 pk;                                                          \
            pk.x = cvtpk(av[it].x, av[it].y);                                  \
            pk.y = cvtpk(av[it].z, av[it].w);                                  \
            *(uint2*)(Aw0 + (buf) * 16384 + it * 2048) = pk;                   \
        }                                                                      \
        _Pragma("unroll")                                                      \
        for (int it = 0; it < 4; ++it)                                         \
            *(uint4*)(Bw0 + (buf) * 16384 + it * 4096) = bvv[it];              \
    }

    LOADTILE(0);
    WRITETILE(0);
    __syncthreads();
    int cur = 0;

    for (int kk = 0; kk < 16; ++kk) {
        if (kk < 15) LOADTILE(kk + 1);
        #pragma unroll
        for (int ks = 0; ks < 2; ++ks) {
            bf16x8 a[4], b[4];
            #pragma unroll
            for (int mt = 0; mt < 4; ++mt) {
                int row = wm * 64 + mt * 16 + c;
                a[mt] = *(const bf16x8*)(&Asb[cur][0] + row * 128 + ((g * 16 + ks * 64) ^ ((c & 7) << 4)));
            }
            #pragma unroll
            for (int nt = 0; nt < 4; ++nt) {
                int rowb = wn * 64 + nt * 16 + c;
                b[nt] = *(const bf16x8*)(&Bsb[cur][0] + rowb * 128 + ((g * 16 + ks * 64) ^ ((c & 7) << 4)));
            }
            __builtin_amdgcn_s_setprio(1);
            #pragma unroll
            for (int mt = 0; mt < 4; ++mt)
                #pragma unroll
                for (int nt = 0; nt < 4; ++nt)
                    acc[mt][nt] = __builtin_amdgcn_mfma_f32_16x16x32_bf16(a[mt], b[nt], acc[mt][nt], 0, 0, 0);
            __builtin_amdgcn_s_setprio(0);
        }
        if (kk < 15) {
            WRITETILE(cur ^ 1);
            __syncthreads();
            cur ^= 1;
        }
    }
    #undef LOADTILE
    #undef WRITETILE

    #pragma unroll
    for (int nt = 0; nt < 4; ++nt) {
        int col = n0 + wn * 64 + nt * 16 + c;
        float bb = bias[col];
        #pragma unroll
        for (int mt = 0; mt < 4; ++mt) {
            int rbase = m0 + wm * 64 + mt * 16 + g * 4;
            #pragma unroll
            for (int r = 0; r < 4; ++r)
                out[(size_t)(rbase + r) * D_ + col] = f2bf(acc[mt][nt][r] + bb);
        }
    }
}

// ---------------- K3: row norms of bf16 [nrows][512] (video reprs)
__global__ __launch_bounds__(256) void rownorm_kernel(const unsigned short* __restrict__ R,
                                                      float* __restrict__ nrm, int nrows) {
    const int row = blockIdx.x * 4 + (threadIdx.x >> 6);
    const int lane = threadIdx.x & 63;
    if (row >= nrows) return;
    uint4 v = ((const uint4*)(R + (size_t)row * D_))[lane];
    float s = 0.f;
    uint32_t wsx[4] = {v.x, v.y, v.z, v.w};
    #pragma unroll
    for (int q = 0; q < 4; ++q) {
        float lo = __uint_as_float(wsx[q] << 16);
        float hi = __uint_as_float(wsx[q] & 0xffff0000u);
        s += lo * lo + hi * hi;
    }
    #pragma unroll
    for (int d = 1; d < 64; d <<= 1) s += __shfl_xor(s, d);
    if (lane == 0) nrm[row] = sqrtf(s);
}

// ---------------- K4: per-item: lgns=log2(ns); Gn (cosine Gram, frag order, bf16);
//                  Sf = S * (1/ns) in frag order (bf16). One block per item i.
__global__ __launch_bounds__(256) void gram_kernel(const unsigned short* __restrict__ S,
                                                   unsigned short* __restrict__ Gn,
                                                   unsigned short* __restrict__ Sf,
                                                   float* __restrict__ lgns) {
    const int i = blockIdx.x;
    const int tid = threadIdx.x, lane = tid & 63, w = tid >> 6;
    const int g = lane >> 4, c = lane & 15;
    const unsigned short* Sp = S + (size_t)i * TS_ * D_;
    __shared__ float rns_sh[64];

    // phase 1: row sumsq -> lgns, rns
    {
        const int row = tid >> 2, q = tid & 3;
        const uint4* rp = (const uint4*)(Sp + (size_t)row * D_ + q * 128);
        float s = 0.f;
        #pragma unroll
        for (int e = 0; e < 16; ++e) {
            uint4 v = rp[e];
            uint32_t wsx[4] = {v.x, v.y, v.z, v.w};
            #pragma unroll
            for (int qq = 0; qq < 4; ++qq) {
                float lo = __uint_as_float(wsx[qq] << 16);
                float hi = __uint_as_float(wsx[qq] & 0xffff0000u);
                s += lo * lo + hi * hi;
            }
        }
        s += __shfl_xor(s, 1);
        s += __shfl_xor(s, 2);
        if (q == 0) {
            rns_sh[row] = rsqrtf(s);
            lgns[i * 64 + row] = 0.5f * log2f(s);
        }
    }
    __syncthreads();

    // phase 2: Gram via MFMA (raw S), normalize, write frag-order bf16
    {
        f32x4 acc[4];
        {
            f32x4 z = {0.f, 0.f, 0.f, 0.f};
            #pragma unroll
            for (int a = 0; a < 4; ++a) acc[a] = z;
        }
        #pragma unroll
        for (int ks = 0; ks < 16; ++ks) {
            bf16x8 a = *(const bf16x8*)(Sp + (size_t)(w * 16 + c) * D_ + ks * 32 + g * 8);
            #pragma unroll
            for (int nt = 0; nt < 4; ++nt) {
                bf16x8 b = *(const bf16x8*)(Sp + (size_t)(nt * 16 + c) * D_ + ks * 32 + g * 8);
                acc[nt] = __builtin_amdgcn_mfma_f32_16x16x32_bf16(a, b, acc[nt], 0, 0, 0);
            }
        }
        #pragma unroll
        for (int nt = 0; nt < 4; ++nt)
            #pragma unroll
            for (int r = 0; r < 4; ++r) {
                int R = w * 16 + g * 4 + r, C = nt * 16 + c;
                float vn = acc[nt][r] * rns_sh[R] * rns_sh[C];
                int idx = (w * 2 + (nt >> 1)) * 512 + (((nt & 1) * 2 + (c >> 3)) * 16 + g * 4 + r) * 8 + (c & 7);
                Gn[(size_t)i * 4096 + idx] = f2bf(vn);
            }
    }

    // phase 3: normalized S in frag order
    #pragma unroll
    for (int t = 0; t < 16; ++t) {
        int idx = t * 256 + tid;
        int ks = idx >> 8, at = (idx >> 6) & 3, ln = idx & 63;
        int row = at * 16 + (ln & 15), gg = ln >> 4;
        uint4 raw = *(const uint4*)(Sp + (size_t)row * D_ + ks * 32 + gg * 8);
        float sc = rns_sh[row];
        uint32_t rw[4] = {raw.x, raw.y, raw.z, raw.w};
        uint4 o;
        uint32_t* op = (uint32_t*)&o;
        #pragma unroll
        for (int q = 0; q < 4; ++q) {
            float lo = __uint_as_float(rw[q] << 16) * sc;
            float hi = __uint_as_float(rw[q] & 0xffff0000u) * sc;
            op[q] = cvtpk(lo, hi);
        }
        *(uint4*)(Sf + (size_t)i * 32768 + idx * 8) = o;
    }
}

// ---------------- K5: pairwise, TWO j's per block, FOUR chunks of 256 v-rows.
// acc[mt][jj*4+at]: mt in {0,1} (32 v-rows/wave/chunk) -> 64 AGPRs, no spills.
__global__ __launch_bounds__(512, 2) void pairwise_kernel(const unsigned short* __restrict__ V,
                                                          const unsigned short* __restrict__ Sf,
                                                          const unsigned short* __restrict__ Gn,
                                                          const float* __restrict__ nv,
                                                          const float* __restrict__ lgns,
                                                          float* __restrict__ outp) {
    __shared__ char Ssh[131072];   // Sf for j0 (64KB) then j1 (64KB), frag order
    __shared__ char Gsh[16384];    // Gn for j0 (8KB), j1 (8KB), frag order
    __shared__ float lgsh[128];    // lgns for j0, j1
    __shared__ float wsum[16];

    const int bid = blockIdx.x;
    const int xcd = bid & 7, slot = bid >> 3;
    const int i = xcd + 8 * (slot >> 4);   // 16 blocks per i, pinned per XCD
    const int jp = slot & 15;              // j = jp*2 + jj
    const int tid = threadIdx.x;
    const int lane = tid & 63, w = tid >> 6;
    const int g = lane >> 4, c = lane & 15;
    const float L2E = 1.4426950408889634f;

    // ---- stage S(2j), G(2j), lg(2j)
    {
        const unsigned short* Sjf = Sf + (size_t)jp * 65536;
        #pragma unroll
        for (int it = 0; it < 16; ++it) {
            int idx = it * 512 + tid;
            *(uint4*)(Ssh + idx * 16) = *(const uint4*)(Sjf + idx * 8);
        }
        const unsigned short* Gp = Gn + (size_t)jp * 8192;
        #pragma unroll
        for (int it = 0; it < 2; ++it) {
            int idx = it * 512 + tid;
            *(uint4*)(Gsh + idx * 16) = *(const uint4*)(Gp + idx * 8);
        }
        if (tid < 32) *(float4*)(lgsh + tid * 4) = *(const float4*)(lgns + jp * 128 + tid * 4);
    }
    __syncthreads();

    const unsigned short* Vb[2];
    #pragma unroll
    for (int mt = 0; mt < 2; ++mt)
        Vb[mt] = V + ((size_t)i * TV_ + w * 32 + mt * 16 + c) * D_ + g * 8;
    const float* nvb = nv + i * TV_ + w * 32 + c;

    float s_run0 = 0.0f, s_run1 = 0.0f;

    for (int chunk = 0; chunk < 4; ++chunk) {
        const size_t coff = (size_t)chunk * 256 * D_;
        f32x4 acc[2][8];   // [mt][jj*4+at]
        {
            f32x4 z = {0.f, 0.f, 0.f, 0.f};
            #pragma unroll
            for (int a = 0; a < 2; ++a)
                #pragma unroll
                for (int b = 0; b < 8; ++b) acc[a][b] = z;
        }
        // explicit V double-buffer over ks
        bf16x8 bcur[2], bnxt[2];
        #pragma unroll
        for (int mt = 0; mt < 2; ++mt) bcur[mt] = *(const bf16x8*)(Vb[mt] + coff);
        #pragma unroll
        for (int ks = 0; ks < 16; ++ks) {
            bf16x8 a[8];
            #pragma unroll
            for (int q = 0; q < 8; ++q)
                a[q] = *(const bf16x8*)(Ssh + ((q >> 2) << 16) + (((ks * 4 + (q & 3))) << 10) + lane * 16);
            if (ks < 15) {
                #pragma unroll
                for (int mt = 0; mt < 2; ++mt)
                    bnxt[mt] = *(const bf16x8*)(Vb[mt] + coff + (ks + 1) * 32);
            }
            __builtin_amdgcn_s_setprio(1);
            #pragma unroll
            for (int mt = 0; mt < 2; ++mt)
                #pragma unroll
                for (int q = 0; q < 8; ++q)
                    acc[mt][q] = __builtin_amdgcn_mfma_f32_16x16x32_bf16(a[q], bcur[mt], acc[mt][q], 0, 0, 0);
            __builtin_amdgcn_s_setprio(0);
            #pragma unroll
            for (int mt = 0; mt < 2; ++mt) bcur[mt] = bnxt[mt];
        }

        float nv4[2], rnv[2];
        #pragma unroll
        for (int mt = 0; mt < 2; ++mt) {
            nv4[mt] = nvb[chunk * 256 + mt * 16];
            rnv[mt] = __builtin_amdgcn_rcpf(nv4[mt]);
        }

        #pragma unroll
        for (int jj = 0; jj < 2; ++jj) {
            float lg[16];
            #pragma unroll
            for (int at = 0; at < 4; ++at) {
                float4 t4 = *(const float4*)(lgsh + jj * 64 + at * 16 + g * 4);
                lg[at * 4 + 0] = t4.x; lg[at * 4 + 1] = t4.y;
                lg[at * 4 + 2] = t4.z; lg[at * 4 + 3] = t4.w;
            }
            float SPC[2], SPQ[2] = {0.f, 0.f};
            uint32_t bfr[2][2][4];   // [mt][ks2][word]
            #pragma unroll
            for (int mt = 0; mt < 2; ++mt) {
                float rnvL = rnv[mt] * L2E;
                float SPCm = 0.f;
                #pragma unroll
                for (int at = 0; at < 4; ++at)
                    #pragma unroll
                    for (int r = 0; r < 4; ++r) {
                        float t = acc[mt][jj * 4 + at][r];
                        float e = exp2f(fmaf(t, rnvL, lg[at * 4 + r]));
                        SPCm = fmaf(e, t, SPCm);
                        acc[mt][jj * 4 + at][r] = e;
                    }
                SPC[mt] = SPCm;
                #pragma unroll
                for (int ks2 = 0; ks2 < 2; ++ks2) {
                    const int a0 = jj * 4 + ks2 * 2, a1 = a0 + 1;
                    uint32_t A  = cvtpk(acc[mt][a0][0], acc[mt][a0][1]);
                    uint32_t Bw = cvtpk(acc[mt][a0][2], acc[mt][a0][3]);
                    uint32_t C  = cvtpk(acc[mt][a1][0], acc[mt][a1][1]);
                    uint32_t Dw = cvtpk(acc[mt][a1][2], acc[mt][a1][3]);
                    swap32(A, C);  swap16(A, C);
                    swap32(Bw, Dw); swap16(Bw, Dw);
                    bfr[mt][ks2][0] = A;  bfr[mt][ks2][1] = Bw;
                    bfr[mt][ks2][2] = C;  bfr[mt][ks2][3] = Dw;
                }
            }
            // P@G: A = Gn frags (LDS), B = P-hat frags (regs)
            #pragma unroll
            for (int st = 0; st < 4; ++st) {
                bf16x8 g0 = *(const bf16x8*)(Gsh + (jj << 13) + ((st * 2 + 0) << 10) + lane * 16);
                bf16x8 g1 = *(const bf16x8*)(Gsh + (jj << 13) + ((st * 2 + 1) << 10) + lane * 16);
                __builtin_amdgcn_s_setprio(1);
                #pragma unroll
                for (int mt = 0; mt < 2; ++mt) {
                    union { uint32_t u[4]; bf16x8 v; } f0, f1;
                    #pragma unroll
                    for (int q = 0; q < 4; ++q) { f0.u[q] = bfr[mt][0][q]; f1.u[q] = bfr[mt][1][q]; }
                    f32x4 d2 = {0.f, 0.f, 0.f, 0.f};
                    d2 = __builtin_amdgcn_mfma_f32_16x16x32_bf16(g0, f0.v, d2, 0, 0, 0);
                    d2 = __builtin_amdgcn_mfma_f32_16x16x32_bf16(g1, f1.v, d2, 0, 0, 0);
                    #pragma unroll
                    for (int r = 0; r < 4; ++r) SPQ[mt] += acc[mt][jj * 4 + st][r] * d2[r];
                }
                __builtin_amdgcn_s_setprio(0);
            }

            #pragma unroll
            for (int mt = 0; mt < 2; ++mt) {
                float SPCm = SPC[mt], SPQm = SPQ[mt];
                SPCm += __shfl_xor(SPCm, 16); SPCm += __shfl_xor(SPCm, 32);
                SPQm += __shfl_xor(SPQm, 16); SPQm += __shfl_xor(SPQm, 32);
                float sc = SPCm * rnv[mt] * rsqrtf(fmaxf(SPQm, 1e-20f));
                float ev = exp2f(sc * L2E);
                if (jj == 0) s_run0 += ev; else s_run1 += ev;
            }
        }
    }

    // sum over c lanes (g-groups hold identical values)
    #pragma unroll
    for (int d = 1; d < 16; d <<= 1) {
        s_run0 += __shfl_xor(s_run0, d);
        s_run1 += __shfl_xor(s_run1, d);
    }
    if (lane == 0) { wsum[w * 2] = s_run0; wsum[w * 2 + 1] = s_run1; }
    __syncthreads();
    if (tid < 2) {
        float total = 0.f;
        #pragma unroll
        for (int ww = 0; ww < 8; ++ww) total += wsum[ww * 2 + tid];
        outp[i * 32 + jp * 2 + tid] = 0.69314718055994531f * log2f(total);
    }
}

extern "C" void kernel_launch(void* const* d_in, const int* in_sizes, int n_in,
                              void* d_out, int out_size, void* d_ws, size_t ws_size,
                              hipStream_t stream) {
    const float* videos    = (const float*)d_in[0];
    const float* sentences = (const float*)d_in[1];
    // d_in[2] = lengths (unused by the reference computation)
    const float* Wv  = (const float*)d_in[3];
    const float* bv  = (const float*)d_in[4];
    const float* Wsn = (const float*)d_in[5];
    const float* bs  = (const float*)d_in[6];
    float* outp = (float*)d_out;

    char* ws = (char*)d_ws;
    unsigned short* Vrep = (unsigned short*)(ws);                 // 32 MB
    unsigned short* Srep = (unsigned short*)(ws + 33554432);      //  2 MB (raw S repr)
    unsigned short* Wt   = (unsigned short*)(ws + 35651584);      //  2 MB; reused as Sf after encoders
    unsigned short* Gn   = (unsigned short*)(ws + 37748736);      //  256 KB (frag-order cosine Gram)
    float*          nv   = (float*)(ws + 38010880);               //  128 KB
    float*          lgns = (float*)(ws + 38141952);               //  8 KB
    unsigned short* Sf   = Wt;   // alias: Wt dead after encoder_gemm completes (stream-ordered)

    transpose_w<<<dim3(32, 16, 2), 256, 0, stream>>>(Wv, Wsn, Wt);
    encoder_gemm<<<1088, 256, 0, stream>>>(videos, sentences, Wt, bv, bs, Vrep, Srep);
    rownorm_kernel<<<8192, 256, 0, stream>>>(Vrep, nv, B_ * TV_);
    gram_kernel<<<B_, 256, 0, stream>>>(Srep, Gn, Sf, lgns);
    pairwise_kernel<<<512, 512, 0, stream>>>(Vrep, Sf, Gn, nv, lgns, outp);
}

// Round 8
// 194.436 us; speedup vs baseline: 1.0754x; 1.0754x over previous
//
#include <hip/hip_runtime.h>
#include <hip/hip_bf16.h>
#include <stdint.h>
#include <math.h>

typedef __attribute__((ext_vector_type(8))) __bf16 bf16x8;
typedef __attribute__((ext_vector_type(4))) float f32x4;

#define B_   32
#define TV_  1024
#define TS_  64
#define DIN_ 1024
#define D_   512

static __device__ __forceinline__ unsigned short f2bf(float f) {
    union { float f; uint32_t u; } x; x.f = f;
    uint32_t r = x.u + 0x7fffu + ((x.u >> 16) & 1u);
    return (unsigned short)(r >> 16);
}
static __device__ __forceinline__ uint32_t cvtpk(float lo, float hi) {
    uint32_t r;
    asm("v_cvt_pk_bf16_f32 %0, %1, %2" : "=v"(r) : "v"(lo), "v"(hi));
    return r;
}
static __device__ __forceinline__ void swap32(uint32_t& a, uint32_t& b) {
    asm volatile("v_permlane32_swap_b32 %0, %1" : "+v"(a), "+v"(b));
}
static __device__ __forceinline__ void swap16(uint32_t& a, uint32_t& b) {
    asm volatile("v_permlane16_swap_b32 %0, %1" : "+v"(a), "+v"(b));
}

// ---------------- K1: transpose + convert weights: Wt[w][n][k] = W[k][n] (bf16)
__global__ __launch_bounds__(256) void transpose_w(const float* __restrict__ Wv,
                                                   const float* __restrict__ Wsn,
                                                   unsigned short* __restrict__ Wt) {
    const int w = blockIdx.z;
    const float* src = w ? Wsn : Wv;
    __shared__ float t[32][33];
    const int k0 = blockIdx.x * 32, n0 = blockIdx.y * 32;
    const int tx = threadIdx.x & 31, ty = threadIdx.x >> 5;
    #pragma unroll
    for (int r = 0; r < 32; r += 8)
        t[r + ty][tx] = src[(size_t)(k0 + r + ty) * D_ + n0 + tx];
    __syncthreads();
    #pragma unroll
    for (int r = 0; r < 32; r += 8)
        Wt[(size_t)w * 524288 + (size_t)(n0 + r + ty) * DIN_ + k0 + tx] = f2bf(t[tx][r + ty]);
}

// ---------------- K2: fused encoder GEMM (video blocks 0..1023, sentence 1024..1087)
// R5-proven structure: single 32KB LDS buffer, 2 barriers/K-step, reg-staged
// A (fp32->bf16 cvtpk) and B, both XOR-swizzled (conflict-free frag reads).
__global__ __launch_bounds__(256) void encoder_gemm(const float* __restrict__ videos,
                                                    const float* __restrict__ sentences,
                                                    const unsigned short* __restrict__ Wt,
                                                    const float* __restrict__ bv,
                                                    const float* __restrict__ bs,
                                                    unsigned short* __restrict__ Vrep,
                                                    unsigned short* __restrict__ Srep) {
    __shared__ char Asb[128 * 128];
    __shared__ char Bsb[128 * 128];
    const int bid = blockIdx.x;
    const float* X; const unsigned short* W; const float* bias; unsigned short* out;
    int m0, n0;
    if (bid < 1024) {
        int xcd = bid & 7, sl = bid >> 3;
        m0 = (xcd * 32 + (sl >> 2)) * 128;   // 4 consecutive same-XCD blocks share an A-panel
        n0 = (sl & 3) * 128;
        X = videos; W = Wt; bias = bv; out = Vrep;
    } else {
        int sb = bid - 1024;
        m0 = (sb >> 2) * 128;
        n0 = (sb & 3) * 128;
        X = sentences; W = Wt + 524288; bias = bs; out = Srep;
    }
    const int tid = threadIdx.x;
    const int lane = tid & 63, wid = tid >> 6;
    const int g = lane >> 4, c = lane & 15;
    const int wm = wid >> 1, wn = wid & 1;

    f32x4 acc[4][4];
    {
        f32x4 z = {0.f, 0.f, 0.f, 0.f};
        #pragma unroll
        for (int a = 0; a < 4; ++a)
            #pragma unroll
            for (int b = 0; b < 4; ++b) acc[a][b] = z;
    }

    for (int kk = 0; kk < 16; ++kk) {
        const int k0 = kk * 64;
        // stage A: fp32 -> bf16, swizzled
        #pragma unroll
        for (int it = 0; it < 8; ++it) {
            int idx = it * 256 + tid;
            int m = idx >> 4, k4 = idx & 15;
            float4 v = *(const float4*)(X + (size_t)(m0 + m) * DIN_ + k0 + k4 * 4);
            uint2 pk;
            pk.x = cvtpk(v.x, v.y);
            pk.y = cvtpk(v.z, v.w);
            *(uint2*)(Asb + m * 128 + ((k4 * 8) ^ ((m & 7) << 4))) = pk;
        }
        // stage B: bf16 copy, swizzled
        #pragma unroll
        for (int it = 0; it < 4; ++it) {
            int idx = it * 256 + tid;
            int n = idx >> 3, kq = idx & 7;
            uint4 v = *(const uint4*)(W + (size_t)(n0 + n) * DIN_ + k0 + kq * 8);
            *(uint4*)(Bsb + n * 128 + ((kq * 16) ^ ((n & 7) << 4))) = v;
        }
        __syncthreads();
        #pragma unroll
        for (int ks = 0; ks < 2; ++ks) {
            bf16x8 a[4], b[4];
            #pragma unroll
            for (int mt = 0; mt < 4; ++mt) {
                int row = wm * 64 + mt * 16 + c;
                a[mt] = *(const bf16x8*)(Asb + row * 128 + ((g * 16 + ks * 64) ^ ((c & 7) << 4)));
            }
            #pragma unroll
            for (int nt = 0; nt < 4; ++nt) {
                int rowb = wn * 64 + nt * 16 + c;
                b[nt] = *(const bf16x8*)(Bsb + rowb * 128 + ((g * 16 + ks * 64) ^ ((c & 7) << 4)));
            }
            __builtin_amdgcn_s_setprio(1);
            #pragma unroll
            for (int mt = 0; mt < 4; ++mt)
                #pragma unroll
                for (int nt = 0; nt < 4; ++nt)
                    acc[mt][nt] = __builtin_amdgcn_mfma_f32_16x16x32_bf16(a[mt], b[nt], acc[mt][nt], 0, 0, 0);
            __builtin_amdgcn_s_setprio(0);
        }
        __syncthreads();
    }

    #pragma unroll
    for (int nt = 0; nt < 4; ++nt) {
        int col = n0 + wn * 64 + nt * 16 + c;
        float bb = bias[col];
        #pragma unroll
        for (int mt = 0; mt < 4; ++mt) {
            int rbase = m0 + wm * 64 + mt * 16 + g * 4;
            #pragma unroll
            for (int r = 0; r < 4; ++r)
                out[(size_t)(rbase + r) * D_ + col] = f2bf(acc[mt][nt][r] + bb);
        }
    }
}

// ---------------- K3: row norms of bf16 [nrows][512] (video reprs)
__global__ __launch_bounds__(256) void rownorm_kernel(const unsigned short* __restrict__ R,
                                                      float* __restrict__ nrm, int nrows) {
    const int row = blockIdx.x * 4 + (threadIdx.x >> 6);
    const int lane = threadIdx.x & 63;
    if (row >= nrows) return;
    uint4 v = ((const uint4*)(R + (size_t)row * D_))[lane];
    float s = 0.f;
    uint32_t wsx[4] = {v.x, v.y, v.z, v.w};
    #pragma unroll
    for (int q = 0; q < 4; ++q) {
        float lo = __uint_as_float(wsx[q] << 16);
        float hi = __uint_as_float(wsx[q] & 0xffff0000u);
        s += lo * lo + hi * hi;
    }
    #pragma unroll
    for (int d = 1; d < 64; d <<= 1) s += __shfl_xor(s, d);
    if (lane == 0) nrm[row] = sqrtf(s);
}

// ---------------- K4: per-item: lgns=log2(ns); Gn (cosine Gram, frag order, bf16);
//                  Sf = S * (1/ns) in frag order (bf16). One block per item i.
__global__ __launch_bounds__(256) void gram_kernel(const unsigned short* __restrict__ S,
                                                   unsigned short* __restrict__ Gn,
                                                   unsigned short* __restrict__ Sf,
                                                   float* __restrict__ lgns) {
    const int i = blockIdx.x;
    const int tid = threadIdx.x, lane = tid & 63, w = tid >> 6;
    const int g = lane >> 4, c = lane & 15;
    const unsigned short* Sp = S + (size_t)i * TS_ * D_;
    __shared__ float rns_sh[64];

    // phase 1: row sumsq -> lgns, rns
    {
        const int row = tid >> 2, q = tid & 3;
        const uint4* rp = (const uint4*)(Sp + (size_t)row * D_ + q * 128);
        float s = 0.f;
        #pragma unroll
        for (int e = 0; e < 16; ++e) {
            uint4 v = rp[e];
            uint32_t wsx[4] = {v.x, v.y, v.z, v.w};
            #pragma unroll
            for (int qq = 0; qq < 4; ++qq) {
                float lo = __uint_as_float(wsx[qq] << 16);
                float hi = __uint_as_float(wsx[qq] & 0xffff0000u);
                s += lo * lo + hi * hi;
            }
        }
        s += __shfl_xor(s, 1);
        s += __shfl_xor(s, 2);
        if (q == 0) {
            rns_sh[row] = rsqrtf(s);
            lgns[i * 64 + row] = 0.5f * log2f(s);
        }
    }
    __syncthreads();

    // phase 2: Gram via MFMA (raw S), normalize, write frag-order bf16
    {
        f32x4 acc[4];
        {
            f32x4 z = {0.f, 0.f, 0.f, 0.f};
            #pragma unroll
            for (int a = 0; a < 4; ++a) acc[a] = z;
        }
        #pragma unroll
        for (int ks = 0; ks < 16; ++ks) {
            bf16x8 a = *(const bf16x8*)(Sp + (size_t)(w * 16 + c) * D_ + ks * 32 + g * 8);
            #pragma unroll
            for (int nt = 0; nt < 4; ++nt) {
                bf16x8 b = *(const bf16x8*)(Sp + (size_t)(nt * 16 + c) * D_ + ks * 32 + g * 8);
                acc[nt] = __builtin_amdgcn_mfma_f32_16x16x32_bf16(a, b, acc[nt], 0, 0, 0);
            }
        }
        #pragma unroll
        for (int nt = 0; nt < 4; ++nt)
            #pragma unroll
            for (int r = 0; r < 4; ++r) {
                int R = w * 16 + g * 4 + r, C = nt * 16 + c;
                float vn = acc[nt][r] * rns_sh[R] * rns_sh[C];
                int idx = (w * 2 + (nt >> 1)) * 512 + (((nt & 1) * 2 + (c >> 3)) * 16 + g * 4 + r) * 8 + (c & 7);
                Gn[(size_t)i * 4096 + idx] = f2bf(vn);
            }
    }

    // phase 3: normalized S in frag order
    #pragma unroll
    for (int t = 0; t < 16; ++t) {
        int idx = t * 256 + tid;
        int ks = idx >> 8, at = (idx >> 6) & 3, ln = idx & 63;
        int row = at * 16 + (ln & 15), gg = ln >> 4;
        uint4 raw = *(const uint4*)(Sp + (size_t)row * D_ + ks * 32 + gg * 8);
        float sc = rns_sh[row];
        uint32_t rw[4] = {raw.x, raw.y, raw.z, raw.w};
        uint4 o;
        uint32_t* op = (uint32_t*)&o;
        #pragma unroll
        for (int q = 0; q < 4; ++q) {
            float lo = __uint_as_float(rw[q] << 16) * sc;
            float hi = __uint_as_float(rw[q] & 0xffff0000u) * sc;
            op[q] = cvtpk(lo, hi);
        }
        *(uint4*)(Sf + (size_t)i * 32768 + idx * 8) = o;
    }
}

// ---------------- K5: pairwise, TWO j's per block, FOUR chunks of 256 v-rows.
// acc[mt][jj*4+at]: mt in {0,1} (32 v-rows/wave/chunk) -> 64 AGPRs, no spills.
__global__ __launch_bounds__(512, 2) void pairwise_kernel(const unsigned short* __restrict__ V,
                                                          const unsigned short* __restrict__ Sf,
                                                          const unsigned short* __restrict__ Gn,
                                                          const float* __restrict__ nv,
                                                          const float* __restrict__ lgns,
                                                          float* __restrict__ outp) {
    __shared__ char Ssh[131072];   // Sf for j0 (64KB) then j1 (64KB), frag order
    __shared__ char Gsh[16384];    // Gn for j0 (8KB), j1 (8KB), frag order
    __shared__ float lgsh[128];    // lgns for j0, j1
    __shared__ float wsum[16];

    const int bid = blockIdx.x;
    const int xcd = bid & 7, slot = bid >> 3;
    const int i = xcd + 8 * (slot >> 4);   // 16 blocks per i, pinned per XCD
    const int jp = slot & 15;              // j = jp*2 + jj
    const int tid = threadIdx.x;
    const int lane = tid & 63, w = tid >> 6;
    const int g = lane >> 4, c = lane & 15;
    const float L2E = 1.4426950408889634f;

    // ---- stage S(2j), G(2j), lg(2j)
    {
        const unsigned short* Sjf = Sf + (size_t)jp * 65536;
        #pragma unroll
        for (int it = 0; it < 16; ++it) {
            int idx = it * 512 + tid;
            *(uint4*)(Ssh + idx * 16) = *(const uint4*)(Sjf + idx * 8);
        }
        const unsigned short* Gp = Gn + (size_t)jp * 8192;
        #pragma unroll
        for (int it = 0; it < 2; ++it) {
            int idx = it * 512 + tid;
            *(uint4*)(Gsh + idx * 16) = *(const uint4*)(Gp + idx * 8);
        }
        if (tid < 32) *(float4*)(lgsh + tid * 4) = *(const float4*)(lgns + jp * 128 + tid * 4);
    }
    __syncthreads();

    const unsigned short* Vb[2];
    #pragma unroll
    for (int mt = 0; mt < 2; ++mt)
        Vb[mt] = V + ((size_t)i * TV_ + w * 32 + mt * 16 + c) * D_ + g * 8;
    const float* nvb = nv + i * TV_ + w * 32 + c;

    float s_run0 = 0.0f, s_run1 = 0.0f;

    for (int chunk = 0; chunk < 4; ++chunk) {
        const size_t coff = (size_t)chunk * 256 * D_;
        f32x4 acc[2][8];   // [mt][jj*4+at]
        {
            f32x4 z = {0.f, 0.f, 0.f, 0.f};
            #pragma unroll
            for (int a = 0; a < 2; ++a)
                #pragma unroll
                for (int b = 0; b < 8; ++b) acc[a][b] = z;
        }
        // explicit V double-buffer over ks
        bf16x8 bcur[2], bnxt[2];
        #pragma unroll
        for (int mt = 0; mt < 2; ++mt) bcur[mt] = *(const bf16x8*)(Vb[mt] + coff);
        #pragma unroll
        for (int ks = 0; ks < 16; ++ks) {
            bf16x8 a[8];
            #pragma unroll
            for (int q = 0; q < 8; ++q)
                a[q] = *(const bf16x8*)(Ssh + ((q >> 2) << 16) + (((ks * 4 + (q & 3))) << 10) + lane * 16);
            if (ks < 15) {
                #pragma unroll
                for (int mt = 0; mt < 2; ++mt)
                    bnxt[mt] = *(const bf16x8*)(Vb[mt] + coff + (ks + 1) * 32);
            }
            __builtin_amdgcn_s_setprio(1);
            #pragma unroll
            for (int mt = 0; mt < 2; ++mt)
                #pragma unroll
                for (int q = 0; q < 8; ++q)
                    acc[mt][q] = __builtin_amdgcn_mfma_f32_16x16x32_bf16(a[q], bcur[mt], acc[mt][q], 0, 0, 0);
            __builtin_amdgcn_s_setprio(0);
            #pragma unroll
            for (int mt = 0; mt < 2; ++mt) bcur[mt] = bnxt[mt];
        }

        float nv4[2], rnv[2];
        #pragma unroll
        for (int mt = 0; mt < 2; ++mt) {
            nv4[mt] = nvb[chunk * 256 + mt * 16];
            rnv[mt] = __builtin_amdgcn_rcpf(nv4[mt]);
        }

        #pragma unroll
        for (int jj = 0; jj < 2; ++jj) {
            float lg[16];
            #pragma unroll
            for (int at = 0; at < 4; ++at) {
                float4 t4 = *(const float4*)(lgsh + jj * 64 + at * 16 + g * 4);
                lg[at * 4 + 0] = t4.x; lg[at * 4 + 1] = t4.y;
                lg[at * 4 + 2] = t4.z; lg[at * 4 + 3] = t4.w;
            }
            float SPC[2], SPQ[2] = {0.f, 0.f};
            uint32_t bfr[2][2][4];   // [mt][ks2][word]
            #pragma unroll
            for (int mt = 0; mt < 2; ++mt) {
                float rnvL = rnv[mt] * L2E;
                float SPCm = 0.f;
                #pragma unroll
                for (int at = 0; at < 4; ++at)
                    #pragma unroll
                    for (int r = 0; r < 4; ++r) {
                        float t = acc[mt][jj * 4 + at][r];
                        float e = exp2f(fmaf(t, rnvL, lg[at * 4 + r]));
                        SPCm = fmaf(e, t, SPCm);
                        acc[mt][jj * 4 + at][r] = e;
                    }
                SPC[mt] = SPCm;
                #pragma unroll
                for (int ks2 = 0; ks2 < 2; ++ks2) {
                    const int a0 = jj * 4 + ks2 * 2, a1 = a0 + 1;
                    uint32_t A  = cvtpk(acc[mt][a0][0], acc[mt][a0][1]);
                    uint32_t Bw = cvtpk(acc[mt][a0][2], acc[mt][a0][3]);
                    uint32_t C  = cvtpk(acc[mt][a1][0], acc[mt][a1][1]);
                    uint32_t Dw = cvtpk(acc[mt][a1][2], acc[mt][a1][3]);
                    swap32(A, C);  swap16(A, C);
                    swap32(Bw, Dw); swap16(Bw, Dw);
                    bfr[mt][ks2][0] = A;  bfr[mt][ks2][1] = Bw;
                    bfr[mt][ks2][2] = C;  bfr[mt][ks2][3] = Dw;
                }
            }
            // P@G: A = Gn frags (LDS), B = P-hat frags (regs)
            #pragma unroll
            for (int st = 0; st < 4; ++st) {
                bf16x8 g0 = *(const bf16x8*)(Gsh + (jj << 13) + ((st * 2 + 0) << 10) + lane * 16);
                bf16x8 g1 = *(const bf16x8*)(Gsh + (jj << 13) + ((st * 2 + 1) << 10) + lane * 16);
                __builtin_amdgcn_s_setprio(1);
                #pragma unroll
                for (int mt = 0; mt < 2; ++mt) {
                    union { uint32_t u[4]; bf16x8 v; } f0, f1;
                    #pragma unroll
                    for (int q = 0; q < 4; ++q) { f0.u[q] = bfr[mt][0][q]; f1.u[q] = bfr[mt][1][q]; }
                    f32x4 d2 = {0.f, 0.f, 0.f, 0.f};
                    d2 = __builtin_amdgcn_mfma_f32_16x16x32_bf16(g0, f0.v, d2, 0, 0, 0);
                    d2 = __builtin_amdgcn_mfma_f32_16x16x32_bf16(g1, f1.v, d2, 0, 0, 0);
                    #pragma unroll
                    for (int r = 0; r < 4; ++r) SPQ[mt] += acc[mt][jj * 4 + st][r] * d2[r];
                }
                __builtin_amdgcn_s_setprio(0);
            }

            #pragma unroll
            for (int mt = 0; mt < 2; ++mt) {
                float SPCm = SPC[mt], SPQm = SPQ[mt];
                SPCm += __shfl_xor(SPCm, 16); SPCm += __shfl_xor(SPCm, 32);
                SPQm += __shfl_xor(SPQm, 16); SPQm += __shfl_xor(SPQm, 32);
                float sc = SPCm * rnv[mt] * rsqrtf(fmaxf(SPQm, 1e-20f));
                float ev = exp2f(sc * L2E);
                if (jj == 0) s_run0 += ev; else s_run1 += ev;
            }
        }
    }

    // sum over c lanes (g-groups hold identical values)
    #pragma unroll
    for (int d = 1; d < 16; d <<= 1) {
        s_run0 += __shfl_xor(s_run0, d);
        s_run1 += __shfl_xor(s_run1, d);
    }
    if (lane == 0) { wsum[w * 2] = s_run0; wsum[w * 2 + 1] = s_run1; }
    __syncthreads();
    if (tid < 2) {
        float total = 0.f;
        #pragma unroll
        for (int ww = 0; ww < 8; ++ww) total += wsum[ww * 2 + tid];
        outp[i * 32 + jp * 2 + tid] = 0.69314718055994531f * log2f(total);
    }
}

extern "C" void kernel_launch(void* const* d_in, const int* in_sizes, int n_in,
                              void* d_out, int out_size, void* d_ws, size_t ws_size,
                              hipStream_t stream) {
    const float* videos    = (const float*)d_in[0];
    const float* sentences = (const float*)d_in[1];
    // d_in[2] = lengths (unused by the reference computation)
    const float* Wv  = (const float*)d_in[3];
    const float* bv  = (const float*)d_in[4];
    const float* Wsn = (const float*)d_in[5];
    const float* bs  = (const float*)d_in[6];
    float* outp = (float*)d_out;

    char* ws = (char*)d_ws;
    unsigned short* Vrep = (unsigned short*)(ws);                 // 32 MB
    unsigned short* Srep = (unsigned short*)(ws + 33554432);      //  2 MB (raw S repr)
    unsigned short* Wt   = (unsigned short*)(ws + 35651584);      //  2 MB; reused as Sf after encoders
    unsigned short* Gn   = (unsigned short*)(ws + 37748736);      //  256 KB (frag-order cosine Gram)
    float*          nv   = (float*)(ws + 38010880);               //  128 KB
    float*          lgns = (float*)(ws + 38141952);               //  8 KB
    unsigned short* Sf   = Wt;   // alias: Wt dead after encoder_gemm completes (stream-ordered)

    transpose_w<<<dim3(32, 16, 2), 256, 0, stream>>>(Wv, Wsn, Wt);
    encoder_gemm<<<1088, 256, 0, stream>>>(videos, sentences, Wt, bv, bs, Vrep, Srep);
    rownorm_kernel<<<8192, 256, 0, stream>>>(Vrep, nv, B_ * TV_);
    gram_kernel<<<B_, 256, 0, stream>>>(Srep, Gn, Sf, lgns);
    pairwise_kernel<<<512, 512, 0, stream>>>(Vrep, Sf, Gn, nv, lgns, outp);
}